// Round 3
// baseline (309.008 us; speedup 1.0000x reference)
//
#include <hip/hip_runtime.h>
#include <hip/hip_bf16.h>

// Sizes fixed by the reference problem.
#define CN 32
#define RN 256
#define DN 512
#define NN 32
#define LN 256

// LDS layout of main kernel (bytes):
//  sAt   : bf16 [256][256] = 131072, 16B-chunk XOR swizzle (chunk ^= r&7)
//  stage : 32768 = double-buffered staging (conS / Gs), 16K per buffer.
//          Softmax ss/den exchange overlays buf1; epilogue reductions
//          (w12s 4K, nsqS2 2K, red) overlay buf0.
//  total : 163840 = 160 KiB (1 block/CU, 8 waves, 2 waves/SIMD, 256-reg
//          budget).
#define STAGE_OFF 131072
#define SMEM_TOTAL 163840

typedef short v8s __attribute__((ext_vector_type(8)));
typedef float v4f __attribute__((ext_vector_type(4)));
typedef const __attribute__((address_space(1))) void* gas1_t;
typedef __attribute__((address_space(3))) void* las3_t;

__device__ __forceinline__ void gl2lds16(const void* g, void* l) {
  __builtin_amdgcn_global_load_lds((gas1_t)g, (las3_t)l, 16, 0, 0);
}

__device__ __forceinline__ unsigned short f2bf(float x) {
  unsigned int u = __float_as_uint(x);
  u = (u + 0x7fffu + ((u >> 16) & 1u)) >> 16;  // RNE
  return (unsigned short)u;
}
__device__ __forceinline__ float bf2f(unsigned short h) {
  return __uint_as_float(((unsigned int)h) << 16);
}

// Packed RNE f32x2 -> bf16x2 (v_cvt_pk_bf16_f32 on gfx950); a -> low 16.
__device__ __forceinline__ unsigned int pkbf(float a, float b) {
  __hip_bfloat162 h = __float22bfloat162_rn(make_float2(a, b));
  unsigned int u;
  __builtin_memcpy(&u, &h, sizeof(u));
  return u;
}

// Staging buffers ([256][32] shorts): 16B chunks XOR-swizzled with (r>>1)&3.
// Writes absorb the swizzle in the global fetch column; reads via this helper.
__device__ __forceinline__ const v8s* stgFrag(const unsigned short* buf, int r,
                                              int quad) {
  return (const v8s*)(buf + r * 32 + ((quad ^ ((r >> 1) & 3)) << 3));
}

// sAt addressing: row-major stride 256 shorts, 16B chunks XOR-swizzled by row.
__device__ __forceinline__ int satIdx(int r, int col) {
  return (r << 8) | ((((col >> 3) ^ (r & 7)) << 3) | (col & 7));
}

// Read an 8-float fragment from the fp32 gram slice [256][64] (32B chunks
// rotated by row) and convert to bf16x8.
__device__ __forceinline__ v8s ldFrag64(const float* buf, int r, int cp) {
  const float* p = buf + r * 64 + (((cp + r) & 7) << 3);
  const float4 x0 = ((const float4*)p)[0];
  const float4 x1 = ((const float4*)p)[1];
  unsigned short h[8];
  h[0] = f2bf(x0.x); h[1] = f2bf(x0.y); h[2] = f2bf(x0.z); h[3] = f2bf(x0.w);
  h[4] = f2bf(x1.x); h[5] = f2bf(x1.y); h[6] = f2bf(x1.z); h[7] = f2bf(x1.w);
  return *(v8s*)h;
}

// ---------------------------------------------------------------------------
// Fused setup: 256 blocks x 512 threads (1 block/CU). Each block: gram
// chunk-0 staging issued first, 1/256th of the bf16 conversions (hides the
// staging latency), then the double-buffered gram K-loop
// (G[n] = laws[n]@laws[n]^T, 32-row output stripe per block).
// ---------------------------------------------------------------------------
__global__ __launch_bounds__(512) void setup_kernel(
    const float* __restrict__ con, const float* __restrict__ laws,
    unsigned short* __restrict__ lawsB, unsigned short* __restrict__ conB,
    float* __restrict__ cnorm, unsigned short* __restrict__ G) {
  extern __shared__ float slice[];  // 2 x [256*64] fp32, row-rotated 32B chunks
  const int bid = blockIdx.x;       // 256 blocks
  const int t = threadIdx.x;
  const int n = bid >> 3;
  const int m0 = (bid & 7) << 5;  // 32-row output stripe of G[n]
  const int lane = t & 63;
  const int w = t >> 6;
  const int quad = lane >> 4;
  const int l16 = lane & 15;
  const int rg = w >> 2;  // 0..1
  const int cg = w & 3;   // 0..3
  const float* lawN = laws + n * (LN * DN);

  // (1) Issue gram chunk-0 staging into buf0 (in flight during conversions).
#pragma unroll
  for (int i = 0; i < 8; ++i) {
    const int s = i * 512 + t;
    const int row = s >> 4;
    const int p = s & 15;
    const int srcCol = ((((p >> 1) - row) & 7) << 3) + ((p & 1) << 2);
    gl2lds16(lawN + row * DN + srcCol, (char*)slice + s * 16);
  }

  // (2a) laws fp32 -> bf16: this block's 16384-float slice.
#pragma unroll
  for (int p = 0; p < 4; ++p) {
    const int off = bid * 16384 + p * 4096 + t * 8;
    const float4* src = (const float4*)(laws + off);
    float4 x0 = src[0], x1 = src[1];
    unsigned short h[8];
    h[0] = f2bf(x0.x); h[1] = f2bf(x0.y); h[2] = f2bf(x0.z); h[3] = f2bf(x0.w);
    h[4] = f2bf(x1.x); h[5] = f2bf(x1.y); h[6] = f2bf(x1.z); h[7] = f2bf(x1.w);
    *(v8s*)(lawsB + off) = *(v8s*)h;
  }
  // (2b) contracts fp32 -> bf16 + row norms: 32 rows (one wave-row per pass).
#pragma unroll
  for (int p = 0; p < 4; ++p) {
    const int r = bid * 32 + p * 8 + w;
    const float4* src = (const float4*)(con + r * DN + lane * 8);
    float4 x0 = src[0], x1 = src[1];
    unsigned short h[8];
    h[0] = f2bf(x0.x); h[1] = f2bf(x0.y); h[2] = f2bf(x0.z); h[3] = f2bf(x0.w);
    h[4] = f2bf(x1.x); h[5] = f2bf(x1.y); h[6] = f2bf(x1.z); h[7] = f2bf(x1.w);
    *(v8s*)(conB + r * DN + lane * 8) = *(v8s*)h;
    float s = x0.x * x0.x + x0.y * x0.y + x0.z * x0.z + x0.w * x0.w +
              x1.x * x1.x + x1.y * x1.y + x1.z * x1.z + x1.w * x1.w;
#pragma unroll
    for (int m = 1; m < 64; m <<= 1) s += __shfl_xor(s, m, 64);
    if (lane == 0) cnorm[r] = sqrtf(s);
  }

  // (3) Gram K-loop, double-buffered.
  v4f acc[4];
#pragma unroll
  for (int b = 0; b < 4; ++b) acc[b] = (v4f){0.f, 0.f, 0.f, 0.f};

  for (int ch = 0; ch < 8; ++ch) {
    __syncthreads();  // buf[ch&1] staged (chunk-ch load has been in flight)
    if (ch < 7) {     // prefetch chunk ch+1 into the other buffer
      const int dk = (ch + 1) << 6;
      char* dst = (char*)slice + ((ch + 1) & 1) * 65536;
#pragma unroll
      for (int i = 0; i < 8; ++i) {
        const int s = i * 512 + t;
        const int row = s >> 4;
        const int p = s & 15;
        const int srcCol = ((((p >> 1) - row) & 7) << 3) + ((p & 1) << 2);
        gl2lds16(lawN + row * DN + dk + srcCol, dst + s * 16);
      }
    }
    const float* buf = slice + (ch & 1) * 16384;
#pragma unroll
    for (int step = 0; step < 2; ++step) {
      const int cp = quad + (step << 2);
      v8s af = ldFrag64(buf, m0 + rg * 16 + l16, cp);
#pragma unroll
      for (int ct = 0; ct < 4; ++ct) {
        v8s bf = ldFrag64(buf, cg * 64 + ct * 16 + l16, cp);
        acc[ct] = __builtin_amdgcn_mfma_f32_16x16x32_bf16(af, bf, acc[ct], 0, 0, 0);
      }
    }
  }
  unsigned short* g = G + n * (LN * LN);
#pragma unroll
  for (int ct = 0; ct < 4; ++ct)
#pragma unroll
    for (int reg = 0; reg < 4; ++reg) {
      const int l = m0 + rg * 16 + quad * 4 + reg;
      g[l * LN + cg * 64 + ct * 16 + l16] = f2bf(acc[ct][reg]);
    }
}

// ---------------------------------------------------------------------------
// Main: one block per (n,c), 512 threads (8 waves). R15: wave tile reorg
// M=64 x N=128 in both MFMA phases (was M=32 x N=256): each B-fragment
// feeds 4 MFMAs instead of 2, halving B-side LDS read traffic (the measured
// bottleneck: ~1536 -> ~768 LDS cyc per K-step per CU in phase A). Softmax
// row stats (ss/den) now span two waves (r-halves) and are combined via an
// LDS exchange overlaying stage buf1 (+2 barriers). The failed R14 nLt cap
// is reverted (runtime guards inside the MFMA loop broke the pipeline).
// ---------------------------------------------------------------------------
__global__ __launch_bounds__(512, 2) void main_kernel(
    const int* __restrict__ law_lens, const unsigned short* __restrict__ lawsB,
    const unsigned short* __restrict__ conB, const unsigned short* __restrict__ Gm,
    const float* __restrict__ cnorm, float* __restrict__ out) {
  extern __shared__ char smem[];
  unsigned short* sAt = (unsigned short*)smem;  // [256][256] swizzled
  char* stage = smem + STAGE_OFF;               // 2 x 16K buffers

  const int bid = blockIdx.x;
  const int n = bid >> 5;  // 32 consecutive blocks share one n
  const int c = bid & 31;
  const int t = threadIdx.x;
  const int lane = t & 63;
  const int w = t >> 6;  // wave 0..7
  const int quad = lane >> 4;
  const int l16 = lane & 15;
  const int sub = t & 3;
  const int rQ = t >> 2;                   // 0..127
  const int subx = sub ^ ((rQ >> 1) & 3);  // swizzled source chunk
  const int len = law_lens[n];
  const int nCh = (len + 31) >> 5;  // phase-B k-chunks (block-uniform)

  // Phase-A wave roles: wl = l-quarter (64 rows), rh = r-half (128 cols).
  // Phase-B wave roles: wr = r-quarter (64 rows), lh = l-half (128 cols).
  const int wl = w & 3;
  const int rh = w >> 2;
  const bool active = (wl * 64) < len;  // pair (wl,rh=0/1) share activity

  const unsigned short* lawN = lawsB + n * (LN * DN);
  const unsigned short* conC = conB + c * (RN * DN);
  const unsigned short* Gn = Gm + n * (LN * LN);

  // Softmax exchange buffers overlay stage buf1 (free until phase-B ch1
  // prefetch, which happens after phase-B's first barrier).
  float* sSS = (float*)(stage + 16384);          // [2][256]
  float* sInv = (float*)(stage + 16384 + 2048);  // [256]
  float* sDen = (float*)(stage + 16384 + 3072);  // [2][256]

  float w12p[8];
#pragma unroll
  for (int i = 0; i < 8; ++i) w12p[i] = 0.f;

  // ---------------- Phase A ----------------
  {
    // A-frag rows: wl*64 + tl*16 + l16, k-offset quad*8.
    const unsigned short* ap = lawN + (wl * 64 + l16) * DN + quad * 8;

    v4f acc[4][8];
#pragma unroll
    for (int a = 0; a < 4; ++a)
#pragma unroll
      for (int b = 0; b < 8; ++b) acc[a][b] = (v4f){0.f, 0.f, 0.f, 0.f};

    // Prologue: stage con chunk 0 into buf0.
#pragma unroll
    for (int i = 0; i < 2; ++i)
      gl2lds16(conC + (i * 128 + rQ) * DN + subx * 8,
               stage + i * 8192 + t * 16);

    for (int ch = 0; ch < 16; ++ch) {
      const int dk = ch << 5;
      __syncthreads();  // drains chunk-ch staging (in flight since iter ch-1)
      // A-frags FIRST (older than prefetch -> auto-wait leaves prefetch live).
      v8s af0 = *(const v8s*)(ap + dk);
      v8s af1 = *(const v8s*)(ap + 16 * DN + dk);
      v8s af2 = *(const v8s*)(ap + 32 * DN + dk);
      v8s af3 = *(const v8s*)(ap + 48 * DN + dk);
      __builtin_amdgcn_sched_barrier(0);
      if (ch < 15) {  // prefetch chunk ch+1 into the other buffer
        char* dst = stage + ((ch + 1) & 1) * 16384;
#pragma unroll
        for (int i = 0; i < 2; ++i)
          gl2lds16(conC + (i * 128 + rQ) * DN + (dk + 32) + subx * 8,
                   dst + i * 8192 + t * 16);
      }
      __builtin_amdgcn_sched_barrier(0);
      if (active) {  // wave-uniform: inactive waves produce only zeros below
        const unsigned short* cs =
            (const unsigned short*)(stage + (ch & 1) * 16384);
#pragma unroll
        for (int rt = 0; rt < 8; ++rt) {
          v8s bf = *stgFrag(cs, rh * 128 + rt * 16 + l16, quad);
          acc[0][rt] = __builtin_amdgcn_mfma_f32_16x16x32_bf16(af0, bf, acc[0][rt], 0, 0, 0);
          acc[1][rt] = __builtin_amdgcn_mfma_f32_16x16x32_bf16(af1, bf, acc[1][rt], 0, 0, 0);
          acc[2][rt] = __builtin_amdgcn_mfma_f32_16x16x32_bf16(af2, bf, acc[2][rt], 0, 0, 0);
          acc[3][rt] = __builtin_amdgcn_mfma_f32_16x16x32_bf16(af3, bf, acc[3][rt], 0, 0, 0);
        }
      }
    }

    __syncthreads();  // all staging reads done; stage buf0 reusable

    // Hoisted: stage G chunk 0 into buf0 NOW -- its latency hides under the
    // softmax VALU below; phase B's first barrier drains it.
#pragma unroll
    for (int i = 0; i < 2; ++i)
      gl2lds16(Gn + (i * 128 + rQ) * LN + subx * 8, stage + i * 8192 + t * 16);

    // Pass 1: per-row ss partials over this wave's 128 r-cols.
    if (active) {
#pragma unroll
      for (int tl = 0; tl < 4; ++tl)
#pragma unroll
        for (int reg = 0; reg < 4; ++reg) {
          const int lg = wl * 64 + tl * 16 + quad * 4 + reg;
          float ss = 0.f;
#pragma unroll
          for (int rt = 0; rt < 8; ++rt) {
            const float v = acc[tl][rt][reg] * 0.04419417382415922f;
            const float lv = v > 0.f ? v : 0.1f * v;
            ss += lv * lv;
          }
#pragma unroll
          for (int m = 1; m < 16; m <<= 1) ss += __shfl_xor(ss, m, 64);
          if (l16 == 0) sSS[rh * 256 + lg] = ss;
        }
    }
    __syncthreads();  // ss exchange visible (ALL waves)

    // Pass 2: inv from total ss; den partials over this wave's 128 r-cols.
    if (active) {
#pragma unroll
      for (int tl = 0; tl < 4; ++tl)
#pragma unroll
        for (int reg = 0; reg < 4; ++reg) {
          const int lg = wl * 64 + tl * 16 + quad * 4 + reg;
          const float inv = 1.f / (sqrtf(sSS[lg] + sSS[256 + lg]) + 1e-8f);
          float den = 0.f;
#pragma unroll
          for (int rt = 0; rt < 8; ++rt) {
            const float v = acc[tl][rt][reg] * 0.04419417382415922f;
            const float lv = v > 0.f ? v : 0.1f * v;
            den += __expf(lv * inv);
          }
#pragma unroll
          for (int m = 1; m < 16; m <<= 1) den += __shfl_xor(den, m, 64);
          if (l16 == 0) {
            sDen[rh * 256 + lg] = den;
            if (rh == 0) sInv[lg] = inv;
          }
        }
    }
    __syncthreads();  // den/inv exchange visible (ALL waves)

    // Pass 3: apply (recompute e from acc + LDS-resident inv/den), pack to
    // sAt, accumulate w12 partials.
    if (active) {
#pragma unroll
      for (int tl = 0; tl < 4; ++tl) {
        unsigned int pk[8][2];
        float a0s[8];
#pragma unroll
        for (int reg = 0; reg < 4; ++reg) {
          const int lg = wl * 64 + tl * 16 + quad * 4 + reg;
          const float inv = sInv[lg];
          const float den = sDen[lg] + sDen[256 + lg];
          const float sc = (lg < len) ? 4.f / den : 0.f;  // SMOOTH, masked
#pragma unroll
          for (int rt = 0; rt < 8; ++rt) {
            const float v = acc[tl][rt][reg] * 0.04419417382415922f;
            const float lv = v > 0.f ? v : 0.1f * v;
            const float a = __expf(lv * inv) * sc;
            w12p[rt] += a * v;  // raw S -> cosine numerator
            if (reg & 1)
              pk[rt][reg >> 1] = pkbf(a0s[rt], a);
            else
              a0s[rt] = a;
          }
        }
        const int lg0 = wl * 64 + tl * 16 + quad * 4;
#pragma unroll
        for (int rt = 0; rt < 8; ++rt)
          *(uint2*)(sAt + satIdx(rh * 128 + rt * 16 + l16, lg0)) =
              *(uint2*)pk[rt];
      }
    } else {
      // Zero this wave's sAt region so downstream reads see exact zeros
      // (attn == 0 beyond len).
      uint2 z;
      z.x = 0u;
      z.y = 0u;
#pragma unroll
      for (int tl = 0; tl < 4; ++tl) {
        const int lg0 = wl * 64 + tl * 16 + quad * 4;
#pragma unroll
        for (int rt = 0; rt < 8; ++rt)
          *(uint2*)(sAt + satIdx(rh * 128 + rt * 16 + l16, lg0)) = z;
      }
    }
  }

  // Combine the 4 quads' row-subsets (same r-cols) -> full w12 partial over
  // this wave's 64 l-rows; kept in registers through phase B.
#pragma unroll
  for (int rt = 0; rt < 8; ++rt) {
    w12p[rt] += __shfl_xor(w12p[rt], 16, 64);
    w12p[rt] += __shfl_xor(w12p[rt], 32, 64);
  }

  // ---------------- Phase B (k capped at nCh = ceil(len/32)) ----------------
  const int wr = w & 3;
  const int lh = w >> 2;
  float nsv[4][4];
  {
    v4f acc[4][8];
#pragma unroll
    for (int a = 0; a < 4; ++a)
#pragma unroll
      for (int b = 0; b < 8; ++b) acc[a][b] = (v4f){0.f, 0.f, 0.f, 0.f};

    for (int ch = 0; ch < nCh; ++ch) {
      const int lk = ch << 5;
      __syncthreads();  // drains chunk-ch Gs staging; ch0 also orders sAt
      v8s af0 = *(const v8s*)(sAt + satIdx(wr * 64 + l16, lk + quad * 8));
      v8s af1 = *(const v8s*)(sAt + satIdx(wr * 64 + 16 + l16, lk + quad * 8));
      v8s af2 = *(const v8s*)(sAt + satIdx(wr * 64 + 32 + l16, lk + quad * 8));
      v8s af3 = *(const v8s*)(sAt + satIdx(wr * 64 + 48 + l16, lk + quad * 8));
      __builtin_amdgcn_sched_barrier(0);
      if (ch < nCh - 1) {  // prefetch chunk ch+1
        char* dst = stage + ((ch + 1) & 1) * 16384;
#pragma unroll
        for (int i = 0; i < 2; ++i)
          gl2lds16(Gn + (i * 128 + rQ) * LN + (lk + 32) + subx * 8,
                   dst + i * 8192 + t * 16);
      }
      __builtin_amdgcn_sched_barrier(0);
      const unsigned short* gs =
          (const unsigned short*)(stage + (ch & 1) * 16384);
#pragma unroll
      for (int lt = 0; lt < 8; ++lt) {
        v8s bf = *stgFrag(gs, lh * 128 + lt * 16 + l16, quad);  // G (symmetric)
        acc[0][lt] = __builtin_amdgcn_mfma_f32_16x16x32_bf16(af0, bf, acc[0][lt], 0, 0, 0);
        acc[1][lt] = __builtin_amdgcn_mfma_f32_16x16x32_bf16(af1, bf, acc[1][lt], 0, 0, 0);
        acc[2][lt] = __builtin_amdgcn_mfma_f32_16x16x32_bf16(af2, bf, acc[2][lt], 0, 0, 0);
        acc[3][lt] = __builtin_amdgcn_mfma_f32_16x16x32_bf16(af3, bf, acc[3][lt], 0, 0, 0);
      }
    }
    // nsq[r] partial = sum over this wave's 128 l-cols of At[r,l] * U[r,l]
    // (sAt cols >= len are exact zeros).
#pragma unroll
    for (int tl = 0; tl < 4; ++tl) {
#pragma unroll
      for (int reg = 0; reg < 4; ++reg) {
        const int r = wr * 64 + tl * 16 + quad * 4 + reg;
        float s = 0.f;
#pragma unroll
        for (int lt = 0; lt < 8; ++lt)
          s += acc[tl][lt][reg] *
               bf2f(sAt[satIdx(r, lh * 128 + lt * 16 + l16)]);
#pragma unroll
        for (int m = 1; m < 16; m <<= 1) s += __shfl_xor(s, m, 64);
        nsv[tl][reg] = s;
      }
    }
  }

  // ---------------- Phase C (reductions overlay the stage region) ----------
  float* w12s = (float*)stage;            // [4][256] = 4K  (row = wl)
  float* nsqS2 = (float*)(stage + 4096);  // [2][256] = 2K  (row = lh)
  float* red = (float*)(stage + 6144);    // [8]
  __syncthreads();  // all Gs/sAt reads done; stage is free for reductions
  if (l16 == 0) {
#pragma unroll
    for (int tl = 0; tl < 4; ++tl)
#pragma unroll
      for (int reg = 0; reg < 4; ++reg)
        nsqS2[lh * 256 + wr * 64 + tl * 16 + quad * 4 + reg] = nsv[tl][reg];
  }
  if (lane < 16) {
#pragma unroll
    for (int rt = 0; rt < 8; ++rt)
      w12s[wl * 256 + rh * 128 + rt * 16 + lane] = w12p[rt];
  }
  __syncthreads();
  float p = 0.f;
  if (t < 256) {
    const float w12 =
        w12s[t] + w12s[256 + t] + w12s[512 + t] + w12s[768 + t];
    const float w1 = cnorm[c * RN + t];
    const float w2 = sqrtf(fmaxf(nsqS2[t] + nsqS2[256 + t], 0.f));
    const float sim = (w12 * 22.627416997969522f) / fmaxf(w1 * w2, 1e-8f);
    p = __expf(6.f * sim);
  }
#pragma unroll
  for (int m = 1; m < 64; m <<= 1) p += __shfl_xor(p, m, 64);
  if (lane == 0) red[w] = p;
  __syncthreads();
  if (t == 0) {
    float s = 0.f;
#pragma unroll
    for (int i = 0; i < 8; ++i) s += red[i];
    out[c * NN + n] = logf(s) / 6.f;
  }
}

// ---------------------------------------------------------------------------
extern "C" void kernel_launch(void* const* d_in, const int* in_sizes, int n_in,
                              void* d_out, int out_size, void* d_ws, size_t ws_size,
                              hipStream_t stream) {
  (void)in_sizes; (void)n_in; (void)out_size;
  const float* contracts = (const float*)d_in[0];
  const float* laws = (const float*)d_in[1];
  const int* law_lens = (const int*)d_in[2];
  float* out = (float*)d_out;

  // Workspace layout (21,004,288 B total)
  unsigned short* lawsB = (unsigned short*)d_ws;  // 8 MiB
  unsigned short* conB = lawsB + NN * LN * DN;    // 8 MiB
  unsigned short* G = conB + CN * RN * DN;        // 4 MiB
  float* cnorm = (float*)(G + NN * LN * LN);      // 32 KiB
  if (ws_size < (size_t)21004288) return;

  hipFuncSetAttribute((const void*)setup_kernel,
                      hipFuncAttributeMaxDynamicSharedMemorySize, 131072);
  hipFuncSetAttribute((const void*)main_kernel,
                      hipFuncAttributeMaxDynamicSharedMemorySize, SMEM_TOTAL);

  // 256 blocks: gram stripe + 1/256th of the bf16 conversions each.
  setup_kernel<<<256, 512, 131072, stream>>>(contracts, laws, lawsB, conB,
                                             cnorm, G);
  main_kernel<<<1024, 512, SMEM_TOTAL, stream>>>(law_lens, lawsB, conB, G,
                                                 cnorm, out);
}

// Round 4
// 282.670 us; speedup vs baseline: 1.0932x; 1.0932x over previous
//
#include <hip/hip_runtime.h>
#include <hip/hip_bf16.h>

// Sizes fixed by the reference problem.
#define CN 32
#define RN 256
#define DN 512
#define NN 32
#define LN 256

// LDS layout of main kernel (bytes):
//  sAt   : bf16 [256][256] = 131072, 16B-chunk XOR swizzle (chunk ^= r&7)
//  stage : 32768 = double-buffered staging (conS / Gs), 16K per buffer.
//          Softmax ss/den exchange overlays buf1; epilogue reductions
//          (w12s 8K, nsqS2 2K, red) overlay buf0.
//  total : 163840 = 160 KiB (1 block/CU).
// R16: 1024 threads (16 waves, 4 waves/SIMD -- was 8 waves / 2 per SIMD at
// 22% occupancy). Wave tile M=32 x N=128: acc halves to 64 f32/lane, fitting
// the 128-reg budget 4 waves/SIMD implies (R15 proved M=64 spills at the
// 256-reg budget; traffic can't shrink, so buy latency-hiding instead).
#define STAGE_OFF 131072
#define SMEM_TOTAL 163840

typedef short v8s __attribute__((ext_vector_type(8)));
typedef float v4f __attribute__((ext_vector_type(4)));
typedef const __attribute__((address_space(1))) void* gas1_t;
typedef __attribute__((address_space(3))) void* las3_t;

__device__ __forceinline__ void gl2lds16(const void* g, void* l) {
  __builtin_amdgcn_global_load_lds((gas1_t)g, (las3_t)l, 16, 0, 0);
}

__device__ __forceinline__ unsigned short f2bf(float x) {
  unsigned int u = __float_as_uint(x);
  u = (u + 0x7fffu + ((u >> 16) & 1u)) >> 16;  // RNE
  return (unsigned short)u;
}
__device__ __forceinline__ float bf2f(unsigned short h) {
  return __uint_as_float(((unsigned int)h) << 16);
}

// Packed RNE f32x2 -> bf16x2 (v_cvt_pk_bf16_f32 on gfx950); a -> low 16.
__device__ __forceinline__ unsigned int pkbf(float a, float b) {
  __hip_bfloat162 h = __float22bfloat162_rn(make_float2(a, b));
  unsigned int u;
  __builtin_memcpy(&u, &h, sizeof(u));
  return u;
}

// Staging buffers ([256][32] shorts): 16B chunks XOR-swizzled with (r>>1)&3.
// Writes absorb the swizzle in the global fetch column; reads via this helper.
__device__ __forceinline__ const v8s* stgFrag(const unsigned short* buf, int r,
                                              int quad) {
  return (const v8s*)(buf + r * 32 + ((quad ^ ((r >> 1) & 3)) << 3));
}

// sAt addressing: row-major stride 256 shorts, 16B chunks XOR-swizzled by row.
__device__ __forceinline__ int satIdx(int r, int col) {
  return (r << 8) | ((((col >> 3) ^ (r & 7)) << 3) | (col & 7));
}

// Read an 8-float fragment from the fp32 gram slice [256][64] (32B chunks
// rotated by row) and convert to bf16x8.
__device__ __forceinline__ v8s ldFrag64(const float* buf, int r, int cp) {
  const float* p = buf + r * 64 + (((cp + r) & 7) << 3);
  const float4 x0 = ((const float4*)p)[0];
  const float4 x1 = ((const float4*)p)[1];
  unsigned short h[8];
  h[0] = f2bf(x0.x); h[1] = f2bf(x0.y); h[2] = f2bf(x0.z); h[3] = f2bf(x0.w);
  h[4] = f2bf(x1.x); h[5] = f2bf(x1.y); h[6] = f2bf(x1.z); h[7] = f2bf(x1.w);
  return *(v8s*)h;
}

// ---------------------------------------------------------------------------
// Fused setup: 256 blocks x 512 threads (1 block/CU). Each block: gram
// chunk-0 staging issued first, 1/256th of the bf16 conversions (hides the
// staging latency), then the double-buffered gram K-loop
// (G[n] = laws[n]@laws[n]^T, 32-row output stripe per block).
// ---------------------------------------------------------------------------
__global__ __launch_bounds__(512) void setup_kernel(
    const float* __restrict__ con, const float* __restrict__ laws,
    unsigned short* __restrict__ lawsB, unsigned short* __restrict__ conB,
    float* __restrict__ cnorm, unsigned short* __restrict__ G) {
  extern __shared__ float slice[];  // 2 x [256*64] fp32, row-rotated 32B chunks
  const int bid = blockIdx.x;       // 256 blocks
  const int t = threadIdx.x;
  const int n = bid >> 3;
  const int m0 = (bid & 7) << 5;  // 32-row output stripe of G[n]
  const int lane = t & 63;
  const int w = t >> 6;
  const int quad = lane >> 4;
  const int l16 = lane & 15;
  const int rg = w >> 2;  // 0..1
  const int cg = w & 3;   // 0..3
  const float* lawN = laws + n * (LN * DN);

  // (1) Issue gram chunk-0 staging into buf0 (in flight during conversions).
#pragma unroll
  for (int i = 0; i < 8; ++i) {
    const int s = i * 512 + t;
    const int row = s >> 4;
    const int p = s & 15;
    const int srcCol = ((((p >> 1) - row) & 7) << 3) + ((p & 1) << 2);
    gl2lds16(lawN + row * DN + srcCol, (char*)slice + s * 16);
  }

  // (2a) laws fp32 -> bf16: this block's 16384-float slice.
#pragma unroll
  for (int p = 0; p < 4; ++p) {
    const int off = bid * 16384 + p * 4096 + t * 8;
    const float4* src = (const float4*)(laws + off);
    float4 x0 = src[0], x1 = src[1];
    unsigned short h[8];
    h[0] = f2bf(x0.x); h[1] = f2bf(x0.y); h[2] = f2bf(x0.z); h[3] = f2bf(x0.w);
    h[4] = f2bf(x1.x); h[5] = f2bf(x1.y); h[6] = f2bf(x1.z); h[7] = f2bf(x1.w);
    *(v8s*)(lawsB + off) = *(v8s*)h;
  }
  // (2b) contracts fp32 -> bf16 + row norms: 32 rows (one wave-row per pass).
#pragma unroll
  for (int p = 0; p < 4; ++p) {
    const int r = bid * 32 + p * 8 + w;
    const float4* src = (const float4*)(con + r * DN + lane * 8);
    float4 x0 = src[0], x1 = src[1];
    unsigned short h[8];
    h[0] = f2bf(x0.x); h[1] = f2bf(x0.y); h[2] = f2bf(x0.z); h[3] = f2bf(x0.w);
    h[4] = f2bf(x1.x); h[5] = f2bf(x1.y); h[6] = f2bf(x1.z); h[7] = f2bf(x1.w);
    *(v8s*)(conB + r * DN + lane * 8) = *(v8s*)h;
    float s = x0.x * x0.x + x0.y * x0.y + x0.z * x0.z + x0.w * x0.w +
              x1.x * x1.x + x1.y * x1.y + x1.z * x1.z + x1.w * x1.w;
#pragma unroll
    for (int m = 1; m < 64; m <<= 1) s += __shfl_xor(s, m, 64);
    if (lane == 0) cnorm[r] = sqrtf(s);
  }

  // (3) Gram K-loop, double-buffered.
  v4f acc[4];
#pragma unroll
  for (int b = 0; b < 4; ++b) acc[b] = (v4f){0.f, 0.f, 0.f, 0.f};

  for (int ch = 0; ch < 8; ++ch) {
    __syncthreads();  // buf[ch&1] staged (chunk-ch load has been in flight)
    if (ch < 7) {     // prefetch chunk ch+1 into the other buffer
      const int dk = (ch + 1) << 6;
      char* dst = (char*)slice + ((ch + 1) & 1) * 65536;
#pragma unroll
      for (int i = 0; i < 8; ++i) {
        const int s = i * 512 + t;
        const int row = s >> 4;
        const int p = s & 15;
        const int srcCol = ((((p >> 1) - row) & 7) << 3) + ((p & 1) << 2);
        gl2lds16(lawN + row * DN + dk + srcCol, dst + s * 16);
      }
    }
    const float* buf = slice + (ch & 1) * 16384;
#pragma unroll
    for (int step = 0; step < 2; ++step) {
      const int cp = quad + (step << 2);
      v8s af = ldFrag64(buf, m0 + rg * 16 + l16, cp);
#pragma unroll
      for (int ct = 0; ct < 4; ++ct) {
        v8s bf = ldFrag64(buf, cg * 64 + ct * 16 + l16, cp);
        acc[ct] = __builtin_amdgcn_mfma_f32_16x16x32_bf16(af, bf, acc[ct], 0, 0, 0);
      }
    }
  }
  unsigned short* g = G + n * (LN * LN);
#pragma unroll
  for (int ct = 0; ct < 4; ++ct)
#pragma unroll
    for (int reg = 0; reg < 4; ++reg) {
      const int l = m0 + rg * 16 + quad * 4 + reg;
      g[l * LN + cg * 64 + ct * 16 + l16] = f2bf(acc[ct][reg]);
    }
}

// ---------------------------------------------------------------------------
// Main: one block per (n,c), 1024 threads (16 waves, 4 waves/SIMD).
// Wave tile M=32 x N=128 in both MFMA phases. Phase-A softmax row stats span
// the two rh-halves -> 3-pass ss/den LDS exchange (R15-proven). No runtime
// guards inside MFMA loops (R14 lesson); k capped at nCh only.
// ---------------------------------------------------------------------------
__global__ __launch_bounds__(1024, 4) void main_kernel(
    const int* __restrict__ law_lens, const unsigned short* __restrict__ lawsB,
    const unsigned short* __restrict__ conB, const unsigned short* __restrict__ Gm,
    const float* __restrict__ cnorm, float* __restrict__ out) {
  extern __shared__ char smem[];
  unsigned short* sAt = (unsigned short*)smem;  // [256][256] swizzled
  char* stage = smem + STAGE_OFF;               // 2 x 16K buffers

  const int bid = blockIdx.x;
  const int n = bid >> 5;  // 32 consecutive blocks share one n
  const int c = bid & 31;
  const int t = threadIdx.x;
  const int lane = t & 63;
  const int w = t >> 6;  // wave 0..15
  const int quad = lane >> 4;
  const int l16 = lane & 15;
  const int sub = t & 3;
  const int rQ = t >> 2;                   // 0..255 (staging row)
  const int subx = sub ^ ((rQ >> 1) & 3);  // swizzled source chunk
  const int len = law_lens[n];
  const int nCh = (len + 31) >> 5;  // phase-B k-chunks (block-uniform)

  // Phase-A wave roles: wl = l-block of 32 (0..7), rh = r-half (0..1).
  // Phase-B wave roles: wr = r-block of 32 (0..7), lh = l-half (0..1).
  const int wl = w & 7;
  const int rh = w >> 3;
  const bool active = (wl * 32) < len;

  const unsigned short* lawN = lawsB + n * (LN * DN);
  const unsigned short* conC = conB + c * (RN * DN);
  const unsigned short* Gn = Gm + n * (LN * LN);

  // Softmax exchange buffers overlay stage buf1 (free between phase-A's last
  // compute (buf1 is ch15's read buffer, drained by the post-loop barrier's
  // successor barriers) and phase-B ch1's prefetch).
  float* sSS = (float*)(stage + 16384);          // [2][256]
  float* sInv = (float*)(stage + 16384 + 2048);  // [256]
  float* sDen = (float*)(stage + 16384 + 3072);  // [2][256]

  float w12p[8];
#pragma unroll
  for (int i = 0; i < 8; ++i) w12p[i] = 0.f;

  // ---------------- Phase A ----------------
  {
    const unsigned short* ap = lawN + (wl * 32 + l16) * DN + quad * 8;

    v4f acc[2][8];
#pragma unroll
    for (int a = 0; a < 2; ++a)
#pragma unroll
      for (int b = 0; b < 8; ++b) acc[a][b] = (v4f){0.f, 0.f, 0.f, 0.f};

    // Prologue: stage con chunk 0 into buf0 (one 16B load per thread).
    gl2lds16(conC + rQ * DN + subx * 8, stage + t * 16);

    for (int ch = 0; ch < 16; ++ch) {
      const int dk = ch << 5;
      __syncthreads();  // drains chunk-ch staging (in flight since iter ch-1)
      // A-frags FIRST (older than prefetch -> auto-wait leaves prefetch live).
      v8s af0 = *(const v8s*)(ap + dk);
      v8s af1 = *(const v8s*)(ap + 16 * DN + dk);
      __builtin_amdgcn_sched_barrier(0);
      if (ch < 15) {  // prefetch chunk ch+1 into the other buffer
        gl2lds16(conC + rQ * DN + (dk + 32) + subx * 8,
                 stage + ((ch + 1) & 1) * 16384 + t * 16);
      }
      __builtin_amdgcn_sched_barrier(0);
      if (active) {  // wave-uniform: inactive waves produce only zeros below
        const unsigned short* cs =
            (const unsigned short*)(stage + (ch & 1) * 16384);
#pragma unroll
        for (int rt = 0; rt < 8; ++rt) {
          v8s bf = *stgFrag(cs, rh * 128 + rt * 16 + l16, quad);
          acc[0][rt] = __builtin_amdgcn_mfma_f32_16x16x32_bf16(af0, bf, acc[0][rt], 0, 0, 0);
          acc[1][rt] = __builtin_amdgcn_mfma_f32_16x16x32_bf16(af1, bf, acc[1][rt], 0, 0, 0);
        }
      }
    }

    __syncthreads();  // all staging reads done; stage buf0 reusable

    // Hoisted: stage G chunk 0 into buf0 NOW -- latency hides under softmax.
    gl2lds16(Gn + rQ * LN + subx * 8, stage + t * 16);

    // Pass 1: per-row ss partials over this wave's 128 r-cols.
    if (active) {
#pragma unroll
      for (int tl = 0; tl < 2; ++tl)
#pragma unroll
        for (int reg = 0; reg < 4; ++reg) {
          const int lg = wl * 32 + tl * 16 + quad * 4 + reg;
          float ss = 0.f;
#pragma unroll
          for (int rt = 0; rt < 8; ++rt) {
            const float v = acc[tl][rt][reg] * 0.04419417382415922f;
            const float lv = v > 0.f ? v : 0.1f * v;
            ss += lv * lv;
          }
#pragma unroll
          for (int m = 1; m < 16; m <<= 1) ss += __shfl_xor(ss, m, 64);
          if (l16 == 0) sSS[rh * 256 + lg] = ss;
        }
    }
    __syncthreads();  // ss exchange visible (ALL waves)

    // Pass 2: inv from total ss; den partials over this wave's 128 r-cols.
    if (active) {
#pragma unroll
      for (int tl = 0; tl < 2; ++tl)
#pragma unroll
        for (int reg = 0; reg < 4; ++reg) {
          const int lg = wl * 32 + tl * 16 + quad * 4 + reg;
          const float inv = 1.f / (sqrtf(sSS[lg] + sSS[256 + lg]) + 1e-8f);
          float den = 0.f;
#pragma unroll
          for (int rt = 0; rt < 8; ++rt) {
            const float v = acc[tl][rt][reg] * 0.04419417382415922f;
            const float lv = v > 0.f ? v : 0.1f * v;
            den += __expf(lv * inv);
          }
#pragma unroll
          for (int m = 1; m < 16; m <<= 1) den += __shfl_xor(den, m, 64);
          if (l16 == 0) {
            sDen[rh * 256 + lg] = den;
            if (rh == 0) sInv[lg] = inv;
          }
        }
    }
    __syncthreads();  // den/inv exchange visible (ALL waves)

    // Pass 3: apply (recompute e from acc + LDS-resident inv/den), pack to
    // sAt, accumulate w12 partials.
    if (active) {
#pragma unroll
      for (int tl = 0; tl < 2; ++tl) {
        unsigned int pk[8][2];
        float a0s[8];
#pragma unroll
        for (int reg = 0; reg < 4; ++reg) {
          const int lg = wl * 32 + tl * 16 + quad * 4 + reg;
          const float inv = sInv[lg];
          const float den = sDen[lg] + sDen[256 + lg];
          const float sc = (lg < len) ? 4.f / den : 0.f;  // SMOOTH, masked
#pragma unroll
          for (int rt = 0; rt < 8; ++rt) {
            const float v = acc[tl][rt][reg] * 0.04419417382415922f;
            const float lv = v > 0.f ? v : 0.1f * v;
            const float a = __expf(lv * inv) * sc;
            w12p[rt] += a * v;  // raw S -> cosine numerator
            if (reg & 1)
              pk[rt][reg >> 1] = pkbf(a0s[rt], a);
            else
              a0s[rt] = a;
          }
        }
        const int lg0 = wl * 32 + tl * 16 + quad * 4;
#pragma unroll
        for (int rt = 0; rt < 8; ++rt)
          *(uint2*)(sAt + satIdx(rh * 128 + rt * 16 + l16, lg0)) =
              *(uint2*)pk[rt];
      }
    } else {
      // Zero this wave's sAt region so downstream reads see exact zeros
      // (attn == 0 beyond len).
      uint2 z;
      z.x = 0u;
      z.y = 0u;
#pragma unroll
      for (int tl = 0; tl < 2; ++tl) {
        const int lg0 = wl * 32 + tl * 16 + quad * 4;
#pragma unroll
        for (int rt = 0; rt < 8; ++rt)
          *(uint2*)(sAt + satIdx(rh * 128 + rt * 16 + l16, lg0)) = z;
      }
    }
  }

  // Combine the 4 quads' row-subsets (same r-cols) -> full w12 partial over
  // this wave's 32 l-rows; kept in registers through phase B.
#pragma unroll
  for (int rt = 0; rt < 8; ++rt) {
    w12p[rt] += __shfl_xor(w12p[rt], 16, 64);
    w12p[rt] += __shfl_xor(w12p[rt], 32, 64);
  }

  // ---------------- Phase B (k capped at nCh = ceil(len/32)) ----------------
  const int wr = w & 7;
  const int lh = w >> 3;
  float nsv[2][4];
  {
    v4f acc[2][8];
#pragma unroll
    for (int a = 0; a < 2; ++a)
#pragma unroll
      for (int b = 0; b < 8; ++b) acc[a][b] = (v4f){0.f, 0.f, 0.f, 0.f};

    for (int ch = 0; ch < nCh; ++ch) {
      const int lk = ch << 5;
      __syncthreads();  // drains chunk-ch Gs staging; ch0 also orders sAt
      v8s af0 = *(const v8s*)(sAt + satIdx(wr * 32 + l16, lk + quad * 8));
      v8s af1 = *(const v8s*)(sAt + satIdx(wr * 32 + 16 + l16, lk + quad * 8));
      __builtin_amdgcn_sched_barrier(0);
      if (ch < nCh - 1) {  // prefetch chunk ch+1
        gl2lds16(Gn + rQ * LN + (lk + 32) + subx * 8,
                 stage + ((ch + 1) & 1) * 16384 + t * 16);
      }
      __builtin_amdgcn_sched_barrier(0);
      const unsigned short* gs =
          (const unsigned short*)(stage + (ch & 1) * 16384);
#pragma unroll
      for (int lt = 0; lt < 8; ++lt) {
        v8s bf = *stgFrag(gs, lh * 128 + lt * 16 + l16, quad);  // G (symmetric)
        acc[0][lt] = __builtin_amdgcn_mfma_f32_16x16x32_bf16(af0, bf, acc[0][lt], 0, 0, 0);
        acc[1][lt] = __builtin_amdgcn_mfma_f32_16x16x32_bf16(af1, bf, acc[1][lt], 0, 0, 0);
      }
    }
    // nsq[r] partial = sum over this wave's 128 l-cols of At[r,l] * U[r,l]
    // (sAt cols >= len are exact zeros).
#pragma unroll
    for (int tl = 0; tl < 2; ++tl) {
#pragma unroll
      for (int reg = 0; reg < 4; ++reg) {
        const int r = wr * 32 + tl * 16 + quad * 4 + reg;
        float s = 0.f;
#pragma unroll
        for (int lt = 0; lt < 8; ++lt)
          s += acc[tl][lt][reg] *
               bf2f(sAt[satIdx(r, lh * 128 + lt * 16 + l16)]);
#pragma unroll
        for (int m = 1; m < 16; m <<= 1) s += __shfl_xor(s, m, 64);
        nsv[tl][reg] = s;
      }
    }
  }

  // ---------------- Phase C (reductions overlay the stage region) ----------
  float* w12s = (float*)stage;            // [8][256] = 8K  (row = wl)
  float* nsqS2 = (float*)(stage + 8192);  // [2][256] = 2K  (row = lh)
  float* red = (float*)(stage + 10240);   // [16]
  __syncthreads();  // all Gs/sAt reads done; stage is free for reductions
  if (l16 == 0) {
#pragma unroll
    for (int tl = 0; tl < 2; ++tl)
#pragma unroll
      for (int reg = 0; reg < 4; ++reg)
        nsqS2[lh * 256 + wr * 32 + tl * 16 + quad * 4 + reg] = nsv[tl][reg];
  }
  if (lane < 16) {
#pragma unroll
    for (int rt = 0; rt < 8; ++rt)
      w12s[wl * 256 + rh * 128 + rt * 16 + lane] = w12p[rt];
  }
  __syncthreads();
  float p = 0.f;
  if (t < 256) {
    float w12 = 0.f;
#pragma unroll
    for (int i = 0; i < 8; ++i) w12 += w12s[i * 256 + t];
    const float w1 = cnorm[c * RN + t];
    const float w2 = sqrtf(fmaxf(nsqS2[t] + nsqS2[256 + t], 0.f));
    const float sim = (w12 * 22.627416997969522f) / fmaxf(w1 * w2, 1e-8f);
    p = __expf(6.f * sim);
  }
#pragma unroll
  for (int m = 1; m < 64; m <<= 1) p += __shfl_xor(p, m, 64);
  if (lane == 0) red[w] = p;
  __syncthreads();
  if (t == 0) {
    float s = 0.f;
#pragma unroll
    for (int i = 0; i < 16; ++i) s += red[i];
    out[c * NN + n] = logf(s) / 6.f;
  }
}

// ---------------------------------------------------------------------------
extern "C" void kernel_launch(void* const* d_in, const int* in_sizes, int n_in,
                              void* d_out, int out_size, void* d_ws, size_t ws_size,
                              hipStream_t stream) {
  (void)in_sizes; (void)n_in; (void)out_size;
  const float* contracts = (const float*)d_in[0];
  const float* laws = (const float*)d_in[1];
  const int* law_lens = (const int*)d_in[2];
  float* out = (float*)d_out;

  // Workspace layout (21,004,288 B total)
  unsigned short* lawsB = (unsigned short*)d_ws;  // 8 MiB
  unsigned short* conB = lawsB + NN * LN * DN;    // 8 MiB
  unsigned short* G = conB + CN * RN * DN;        // 4 MiB
  float* cnorm = (float*)(G + NN * LN * LN);      // 32 KiB
  if (ws_size < (size_t)21004288) return;

  hipFuncSetAttribute((const void*)setup_kernel,
                      hipFuncAttributeMaxDynamicSharedMemorySize, 131072);
  hipFuncSetAttribute((const void*)main_kernel,
                      hipFuncAttributeMaxDynamicSharedMemorySize, SMEM_TOTAL);

  // 256 blocks: gram stripe + 1/256th of the bf16 conversions each.
  setup_kernel<<<256, 512, 131072, stream>>>(contracts, laws, lawsB, conB,
                                             cnorm, G);
  main_kernel<<<1024, 1024, SMEM_TOTAL, stream>>>(law_lens, lawsB, conB, G,
                                                  cnorm, out);
}

// Round 5
// 227.546 us; speedup vs baseline: 1.3580x; 1.2423x over previous
//
#include <hip/hip_runtime.h>
#include <hip/hip_bf16.h>

// Sizes fixed by the reference problem.
#define CN 32
#define RN 256
#define DN 512
#define NN 32
#define LN 256

// LDS layout of main kernel (bytes):
//  sAt   : bf16 [256][256] = 131072, 16B-chunk XOR swizzle (chunk ^= r&7)
//  stage : 32768 = double-buffered staging (conS / Gs), 16K per buffer.
//          Epilogue reductions (w12s 8K, nsqS 1K, red) overlay this region.
//  total : 163840 = 160 KiB.
// Shape is boxed (R15/R16 evidence): 512 threads / 8 waves / 2 per SIMD is
// the ONLY config where acc (128 AGPR) + working set fit the 256-reg/wave
// budget. 16-wave blocks cap at 128 regs/wave -> spill (R16: WRITE_SIZE
// 10KB -> 24.5MB); M=64 wave tiles need 128 AGPR + 32 af VGPR -> spill (R15).
#define STAGE_OFF 131072
#define SMEM_TOTAL 163840

typedef short v8s __attribute__((ext_vector_type(8)));
typedef float v4f __attribute__((ext_vector_type(4)));
typedef const __attribute__((address_space(1))) void* gas1_t;
typedef __attribute__((address_space(3))) void* las3_t;

__device__ __forceinline__ void gl2lds16(const void* g, void* l) {
  __builtin_amdgcn_global_load_lds((gas1_t)g, (las3_t)l, 16, 0, 0);
}

__device__ __forceinline__ unsigned short f2bf(float x) {
  unsigned int u = __float_as_uint(x);
  u = (u + 0x7fffu + ((u >> 16) & 1u)) >> 16;  // RNE
  return (unsigned short)u;
}
__device__ __forceinline__ float bf2f(unsigned short h) {
  return __uint_as_float(((unsigned int)h) << 16);
}

// Packed RNE f32x2 -> bf16x2 (v_cvt_pk_bf16_f32 on gfx950); a -> low 16.
__device__ __forceinline__ unsigned int pkbf(float a, float b) {
  __hip_bfloat162 h = __float22bfloat162_rn(make_float2(a, b));
  unsigned int u;
  __builtin_memcpy(&u, &h, sizeof(u));
  return u;
}

// Staging buffers ([256][32] shorts): 16B chunks XOR-swizzled with (r>>1)&3.
// Writes absorb the swizzle in the global fetch column; reads via this helper.
__device__ __forceinline__ const v8s* stgFrag(const unsigned short* buf, int r,
                                              int quad) {
  return (const v8s*)(buf + r * 32 + ((quad ^ ((r >> 1) & 3)) << 3));
}

// sAt addressing: row-major stride 256 shorts, 16B chunks XOR-swizzled by row.
__device__ __forceinline__ int satIdx(int r, int col) {
  return (r << 8) | ((((col >> 3) ^ (r & 7)) << 3) | (col & 7));
}

// Read an 8-float fragment from the fp32 gram slice [256][64] (32B chunks
// rotated by row) and convert to bf16x8.
__device__ __forceinline__ v8s ldFrag64(const float* buf, int r, int cp) {
  const float* p = buf + r * 64 + (((cp + r) & 7) << 3);
  const float4 x0 = ((const float4*)p)[0];
  const float4 x1 = ((const float4*)p)[1];
  unsigned short h[8];
  h[0] = f2bf(x0.x); h[1] = f2bf(x0.y); h[2] = f2bf(x0.z); h[3] = f2bf(x0.w);
  h[4] = f2bf(x1.x); h[5] = f2bf(x1.y); h[6] = f2bf(x1.z); h[7] = f2bf(x1.w);
  return *(v8s*)h;
}

// ---------------------------------------------------------------------------
// Fused setup: 256 blocks x 512 threads (1 block/CU). Each block: gram
// chunk-0 staging issued first, 1/256th of the bf16 conversions (hides the
// staging latency), then the double-buffered gram K-loop
// (G[n] = laws[n]@laws[n]^T, 32-row output stripe per block).
// ---------------------------------------------------------------------------
__global__ __launch_bounds__(512) void setup_kernel(
    const float* __restrict__ con, const float* __restrict__ laws,
    unsigned short* __restrict__ lawsB, unsigned short* __restrict__ conB,
    float* __restrict__ cnorm, unsigned short* __restrict__ G) {
  extern __shared__ float slice[];  // 2 x [256*64] fp32, row-rotated 32B chunks
  const int bid = blockIdx.x;       // 256 blocks
  const int t = threadIdx.x;
  const int n = bid >> 3;
  const int m0 = (bid & 7) << 5;  // 32-row output stripe of G[n]
  const int lane = t & 63;
  const int w = t >> 6;
  const int quad = lane >> 4;
  const int l16 = lane & 15;
  const int rg = w >> 2;  // 0..1
  const int cg = w & 3;   // 0..3
  const float* lawN = laws + n * (LN * DN);

  // (1) Issue gram chunk-0 staging into buf0 (in flight during conversions).
#pragma unroll
  for (int i = 0; i < 8; ++i) {
    const int s = i * 512 + t;
    const int row = s >> 4;
    const int p = s & 15;
    const int srcCol = ((((p >> 1) - row) & 7) << 3) + ((p & 1) << 2);
    gl2lds16(lawN + row * DN + srcCol, (char*)slice + s * 16);
  }

  // (2a) laws fp32 -> bf16: this block's 16384-float slice.
#pragma unroll
  for (int p = 0; p < 4; ++p) {
    const int off = bid * 16384 + p * 4096 + t * 8;
    const float4* src = (const float4*)(laws + off);
    float4 x0 = src[0], x1 = src[1];
    unsigned short h[8];
    h[0] = f2bf(x0.x); h[1] = f2bf(x0.y); h[2] = f2bf(x0.z); h[3] = f2bf(x0.w);
    h[4] = f2bf(x1.x); h[5] = f2bf(x1.y); h[6] = f2bf(x1.z); h[7] = f2bf(x1.w);
    *(v8s*)(lawsB + off) = *(v8s*)h;
  }
  // (2b) contracts fp32 -> bf16 + row norms: 32 rows (one wave-row per pass).
#pragma unroll
  for (int p = 0; p < 4; ++p) {
    const int r = bid * 32 + p * 8 + w;
    const float4* src = (const float4*)(con + r * DN + lane * 8);
    float4 x0 = src[0], x1 = src[1];
    unsigned short h[8];
    h[0] = f2bf(x0.x); h[1] = f2bf(x0.y); h[2] = f2bf(x0.z); h[3] = f2bf(x0.w);
    h[4] = f2bf(x1.x); h[5] = f2bf(x1.y); h[6] = f2bf(x1.z); h[7] = f2bf(x1.w);
    *(v8s*)(conB + r * DN + lane * 8) = *(v8s*)h;
    float s = x0.x * x0.x + x0.y * x0.y + x0.z * x0.z + x0.w * x0.w +
              x1.x * x1.x + x1.y * x1.y + x1.z * x1.z + x1.w * x1.w;
#pragma unroll
    for (int m = 1; m < 64; m <<= 1) s += __shfl_xor(s, m, 64);
    if (lane == 0) cnorm[r] = sqrtf(s);
  }

  // (3) Gram K-loop, double-buffered.
  v4f acc[4];
#pragma unroll
  for (int b = 0; b < 4; ++b) acc[b] = (v4f){0.f, 0.f, 0.f, 0.f};

  for (int ch = 0; ch < 8; ++ch) {
    __syncthreads();  // buf[ch&1] staged (chunk-ch load has been in flight)
    if (ch < 7) {     // prefetch chunk ch+1 into the other buffer
      const int dk = (ch + 1) << 6;
      char* dst = (char*)slice + ((ch + 1) & 1) * 65536;
#pragma unroll
      for (int i = 0; i < 8; ++i) {
        const int s = i * 512 + t;
        const int row = s >> 4;
        const int p = s & 15;
        const int srcCol = ((((p >> 1) - row) & 7) << 3) + ((p & 1) << 2);
        gl2lds16(lawN + row * DN + dk + srcCol, dst + s * 16);
      }
    }
    const float* buf = slice + (ch & 1) * 16384;
#pragma unroll
    for (int step = 0; step < 2; ++step) {
      const int cp = quad + (step << 2);
      v8s af = ldFrag64(buf, m0 + rg * 16 + l16, cp);
#pragma unroll
      for (int ct = 0; ct < 4; ++ct) {
        v8s bf = ldFrag64(buf, cg * 64 + ct * 16 + l16, cp);
        acc[ct] = __builtin_amdgcn_mfma_f32_16x16x32_bf16(af, bf, acc[ct], 0, 0, 0);
      }
    }
  }
  unsigned short* g = G + n * (LN * LN);
#pragma unroll
  for (int ct = 0; ct < 4; ++ct)
#pragma unroll
    for (int reg = 0; reg < 4; ++reg) {
      const int l = m0 + rg * 16 + quad * 4 + reg;
      g[l * LN + cg * 64 + ct * 16 + l16] = f2bf(acc[ct][reg]);
    }
}

// ---------------------------------------------------------------------------
// Main: one block per (n,c), 512 threads (8 waves). R13 structure (best
// measured: 163us) + R17 change: phase-A A-fragments are register
// double-buffered (afA/afB, 2-chunk unrolled loop). Previously the two af
// global loads were issued right after each barrier and consumed by the
// first MFMA -> ~16 x 200-400cyc exposed L2 latency per wave. Now af(ch+1)
// is issued during chunk ch's compute and drained for free by the next
// barrier. Costs +8 VGPR (120->~128; 256-budget exactly with 128 AGPR).
// ---------------------------------------------------------------------------
__global__ __launch_bounds__(512, 2) void main_kernel(
    const int* __restrict__ law_lens, const unsigned short* __restrict__ lawsB,
    const unsigned short* __restrict__ conB, const unsigned short* __restrict__ Gm,
    const float* __restrict__ cnorm, float* __restrict__ out) {
  extern __shared__ char smem[];
  unsigned short* sAt = (unsigned short*)smem;  // [256][256] swizzled
  char* stage = smem + STAGE_OFF;               // 2 x 16K buffers

  const int bid = blockIdx.x;
  const int n = bid >> 5;  // 32 consecutive blocks share one n
  const int c = bid & 31;
  const int t = threadIdx.x;
  const int lane = t & 63;
  const int w = t >> 6;  // wave 0..7
  const int quad = lane >> 4;
  const int l16 = lane & 15;
  const int sub = t & 3;
  const int rQ = t >> 2;                   // 0..127
  const int subx = sub ^ ((rQ >> 1) & 3);  // swizzled source chunk
  const int len = law_lens[n];
  const int nCh = (len + 31) >> 5;         // phase-B k-chunks (block-uniform)
  const bool active = (w * 32) < len;      // wave has live l-rows in phase A

  const unsigned short* lawN = lawsB + n * (LN * DN);
  const unsigned short* conC = conB + c * (RN * DN);
  const unsigned short* Gn = Gm + n * (LN * LN);

  float w12p[16];
#pragma unroll
  for (int i = 0; i < 16; ++i) w12p[i] = 0.f;

  // ---------------- Phase A ----------------
  {
    const unsigned short* a0p = lawN + (w * 32 + l16) * DN + quad * 8;
    const unsigned short* a1p = a0p + 16 * DN;

    v4f acc[2][16];
#pragma unroll
    for (int a = 0; a < 2; ++a)
#pragma unroll
      for (int b = 0; b < 16; ++b) acc[a][b] = (v4f){0.f, 0.f, 0.f, 0.f};

    // Prologue: stage con chunk 0 into buf0 + load af(chunk 0) into afA.
#pragma unroll
    for (int i = 0; i < 2; ++i)
      gl2lds16(conC + (i * 128 + rQ) * DN + subx * 8,
               stage + i * 8192 + t * 16);
    v8s afA0 = *(const v8s*)(a0p);
    v8s afA1 = *(const v8s*)(a1p);

#pragma unroll
    for (int ch = 0; ch < 16; ch += 2) {
      // ---- even chunk ch: compute from buf0 with afA; prefetch ch+1 ----
      __syncthreads();  // drains chunk-ch staging + afA loads (all overlapped)
      v8s afB0, afB1;
      {
        const int dkn = (ch + 1) << 5;  // ch+1 <= 15 always here
#pragma unroll
        for (int i = 0; i < 2; ++i)
          gl2lds16(conC + (i * 128 + rQ) * DN + dkn + subx * 8,
                   stage + 16384 + i * 8192 + t * 16);
        afB0 = *(const v8s*)(a0p + dkn);
        afB1 = *(const v8s*)(a1p + dkn);
      }
      __builtin_amdgcn_sched_barrier(0);
      if (active) {  // wave-uniform: inactive waves produce only zeros below
        const unsigned short* cs = (const unsigned short*)stage;
#pragma unroll
        for (int rt = 0; rt < 16; ++rt) {
          v8s bf = *stgFrag(cs, rt * 16 + l16, quad);
          acc[0][rt] = __builtin_amdgcn_mfma_f32_16x16x32_bf16(afA0, bf, acc[0][rt], 0, 0, 0);
          acc[1][rt] = __builtin_amdgcn_mfma_f32_16x16x32_bf16(afA1, bf, acc[1][rt], 0, 0, 0);
        }
      }
      // ---- odd chunk ch+1: compute from buf1 with afB; prefetch ch+2 ----
      __syncthreads();  // drains chunk-(ch+1) staging + afB loads
      if (ch + 2 < 16) {
        const int dkn = (ch + 2) << 5;
#pragma unroll
        for (int i = 0; i < 2; ++i)
          gl2lds16(conC + (i * 128 + rQ) * DN + dkn + subx * 8,
                   stage + i * 8192 + t * 16);
        afA0 = *(const v8s*)(a0p + dkn);
        afA1 = *(const v8s*)(a1p + dkn);
      }
      __builtin_amdgcn_sched_barrier(0);
      if (active) {
        const unsigned short* cs = (const unsigned short*)(stage + 16384);
#pragma unroll
        for (int rt = 0; rt < 16; ++rt) {
          v8s bf = *stgFrag(cs, rt * 16 + l16, quad);
          acc[0][rt] = __builtin_amdgcn_mfma_f32_16x16x32_bf16(afB0, bf, acc[0][rt], 0, 0, 0);
          acc[1][rt] = __builtin_amdgcn_mfma_f32_16x16x32_bf16(afB1, bf, acc[1][rt], 0, 0, 0);
        }
      }
    }

    __syncthreads();  // all staging reads done; stage buf0 reusable

    // Hoisted: stage G chunk 0 into buf0 NOW -- its latency hides under the
    // softmax VALU below; phase B's first barrier drains it.
#pragma unroll
    for (int i = 0; i < 2; ++i)
      gl2lds16(Gn + (i * 128 + rQ) * LN + subx * 8, stage + i * 8192 + t * 16);

    if (active) {
      // Softmax row ops (streaming; |lv*inv| <= 1 so exp needs no max-sub).
      // Row l lives in 16 lanes (C layout col=lane&15 -> r index). 4 regs =
      // 4 consecutive sAt columns -> packed cvt + b64 writes.
#pragma unroll
      for (int tl = 0; tl < 2; ++tl) {
        unsigned int pk[16][2];
        float a0s[16];
#pragma unroll
        for (int reg = 0; reg < 4; ++reg) {
          const int lg = w * 32 + tl * 16 + quad * 4 + reg;
          float ss = 0.f;
#pragma unroll
          for (int rt = 0; rt < 16; ++rt) {
            const float v = acc[tl][rt][reg] * 0.04419417382415922f;
            const float lv = v > 0.f ? v : 0.1f * v;
            ss += lv * lv;
          }
#pragma unroll
          for (int m = 1; m < 16; m <<= 1) ss += __shfl_xor(ss, m, 64);
          const float inv = 1.f / (sqrtf(ss) + 1e-8f);
          float e[16];
          float den = 0.f;
#pragma unroll
          for (int rt = 0; rt < 16; ++rt) {
            const float v = acc[tl][rt][reg] * 0.04419417382415922f;
            const float lv = v > 0.f ? v : 0.1f * v;
            e[rt] = __expf(lv * inv);
            den += e[rt];
          }
#pragma unroll
          for (int m = 1; m < 16; m <<= 1) den += __shfl_xor(den, m, 64);
          const float sc = (lg < len) ? 4.f / den : 0.f;  // SMOOTH, masked
#pragma unroll
          for (int rt = 0; rt < 16; ++rt) {
            const float v = acc[tl][rt][reg] * 0.04419417382415922f;
            const float a = e[rt] * sc;
            w12p[rt] += a * v;  // raw S -> cosine numerator
            if (reg & 1)
              pk[rt][reg >> 1] = pkbf(a0s[rt], a);
            else
              a0s[rt] = a;
          }
        }
        const int lg0 = w * 32 + tl * 16 + quad * 4;
#pragma unroll
        for (int rt = 0; rt < 16; ++rt)
          *(uint2*)(sAt + satIdx(rt * 16 + l16, lg0)) = *(uint2*)pk[rt];
      }
    } else {
      // Zero this wave's sAt columns so nsq's full-width reads see exact
      // zeros (attn == 0 beyond len).
      uint2 z;
      z.x = 0u;
      z.y = 0u;
#pragma unroll
      for (int tl = 0; tl < 2; ++tl) {
        const int lg0 = w * 32 + tl * 16 + quad * 4;
#pragma unroll
        for (int rt = 0; rt < 16; ++rt)
          *(uint2*)(sAt + satIdx(rt * 16 + l16, lg0)) = z;
      }
    }
  }

  // Reduce w12 partials across quads; keep in registers through phase B.
  // (Inactive waves contribute zeros.)
#pragma unroll
  for (int rt = 0; rt < 16; ++rt) {
    w12p[rt] += __shfl_xor(w12p[rt], 16, 64);
    w12p[rt] += __shfl_xor(w12p[rt], 32, 64);
  }

  // ---------------- Phase B (k capped at nCh = ceil(len/32)) ----------------
  float nsv[2][4];
  {
    v4f acc[2][16];
#pragma unroll
    for (int a = 0; a < 2; ++a)
#pragma unroll
      for (int b = 0; b < 16; ++b) acc[a][b] = (v4f){0.f, 0.f, 0.f, 0.f};

    for (int ch = 0; ch < nCh; ++ch) {
      const int lk = ch << 5;
      __syncthreads();  // drains chunk-ch Gs staging; ch0 also orders sAt
      v8s af0 = *(const v8s*)(sAt + satIdx(w * 32 + l16, lk + quad * 8));
      v8s af1 = *(const v8s*)(sAt + satIdx(w * 32 + 16 + l16, lk + quad * 8));
      __builtin_amdgcn_sched_barrier(0);
      if (ch < nCh - 1) {  // prefetch chunk ch+1
        char* dst = stage + ((ch + 1) & 1) * 16384;
#pragma unroll
        for (int i = 0; i < 2; ++i)
          gl2lds16(Gn + (i * 128 + rQ) * LN + (lk + 32) + subx * 8,
                   dst + i * 8192 + t * 16);
      }
      __builtin_amdgcn_sched_barrier(0);
      const unsigned short* gs =
          (const unsigned short*)(stage + (ch & 1) * 16384);
#pragma unroll
      for (int lt = 0; lt < 16; ++lt) {
        v8s bf = *stgFrag(gs, lt * 16 + l16, quad);  // G row (symmetric)
        acc[0][lt] = __builtin_amdgcn_mfma_f32_16x16x32_bf16(af0, bf, acc[0][lt], 0, 0, 0);
        acc[1][lt] = __builtin_amdgcn_mfma_f32_16x16x32_bf16(af1, bf, acc[1][lt], 0, 0, 0);
      }
    }
    // nsq[r] = sum_l At[r,l] * U[r,l] (sAt cols >= len are exact zeros)
#pragma unroll
    for (int tl = 0; tl < 2; ++tl) {
#pragma unroll
      for (int reg = 0; reg < 4; ++reg) {
        const int r = w * 32 + tl * 16 + quad * 4 + reg;
        float s = 0.f;
#pragma unroll
        for (int lt = 0; lt < 16; ++lt)
          s += acc[tl][lt][reg] * bf2f(sAt[satIdx(r, lt * 16 + l16)]);
#pragma unroll
        for (int m = 1; m < 16; m <<= 1) s += __shfl_xor(s, m, 64);
        nsv[tl][reg] = s;
      }
    }
  }

  // ---------------- Phase C (reductions overlay the stage region) ----------
  float* w12s = (float*)stage;           // [8][256] = 8K
  float* nsqS = (float*)(stage + 8192);  // [256]    = 1K
  float* red = (float*)(stage + 9216);   // [8]
  __syncthreads();  // all Gs reads done; stage is free for reductions
  if (l16 == 0) {
#pragma unroll
    for (int tl = 0; tl < 2; ++tl)
#pragma unroll
      for (int reg = 0; reg < 4; ++reg)
        nsqS[w * 32 + tl * 16 + quad * 4 + reg] = nsv[tl][reg];
  }
  if (lane < 16) {
#pragma unroll
    for (int rt = 0; rt < 16; ++rt) w12s[w * 256 + rt * 16 + lane] = w12p[rt];
  }
  __syncthreads();
  float p = 0.f;
  if (t < 256) {
    float w12 = 0.f;
#pragma unroll
    for (int i = 0; i < 8; ++i) w12 += w12s[i * 256 + t];
    const float w1 = cnorm[c * RN + t];
    const float w2 = sqrtf(fmaxf(nsqS[t], 0.f));
    const float sim = (w12 * 22.627416997969522f) / fmaxf(w1 * w2, 1e-8f);
    p = __expf(6.f * sim);
  }
#pragma unroll
  for (int m = 1; m < 64; m <<= 1) p += __shfl_xor(p, m, 64);
  if (lane == 0) red[w] = p;
  __syncthreads();
  if (t == 0) {
    float s = 0.f;
#pragma unroll
    for (int i = 0; i < 8; ++i) s += red[i];
    out[c * NN + n] = logf(s) / 6.f;
  }
}

// ---------------------------------------------------------------------------
extern "C" void kernel_launch(void* const* d_in, const int* in_sizes, int n_in,
                              void* d_out, int out_size, void* d_ws, size_t ws_size,
                              hipStream_t stream) {
  (void)in_sizes; (void)n_in; (void)out_size;
  const float* contracts = (const float*)d_in[0];
  const float* laws = (const float*)d_in[1];
  const int* law_lens = (const int*)d_in[2];
  float* out = (float*)d_out;

  // Workspace layout (21,004,288 B total)
  unsigned short* lawsB = (unsigned short*)d_ws;  // 8 MiB
  unsigned short* conB = lawsB + NN * LN * DN;    // 8 MiB
  unsigned short* G = conB + CN * RN * DN;        // 4 MiB
  float* cnorm = (float*)(G + NN * LN * LN);      // 32 KiB
  if (ws_size < (size_t)21004288) return;

  hipFuncSetAttribute((const void*)setup_kernel,
                      hipFuncAttributeMaxDynamicSharedMemorySize, 131072);
  hipFuncSetAttribute((const void*)main_kernel,
                      hipFuncAttributeMaxDynamicSharedMemorySize, SMEM_TOTAL);

  // 256 blocks: gram stripe + 1/256th of the bf16 conversions each.
  setup_kernel<<<256, 512, 131072, stream>>>(contracts, laws, lawsB, conB,
                                             cnorm, G);
  main_kernel<<<1024, 512, SMEM_TOTAL, stream>>>(law_lens, lawsB, conB, G,
                                                 cnorm, out);
}

// Round 6
// 225.001 us; speedup vs baseline: 1.3734x; 1.0113x over previous
//
#include <hip/hip_runtime.h>
#include <hip/hip_bf16.h>

// Sizes fixed by the reference problem.
#define CN 32
#define RN 256
#define DN 512
#define NN 32
#define LN 256

// LDS layout of main kernel (bytes):
//  sAt   : bf16 [256][256] = 131072, 16B-chunk XOR swizzle (chunk ^= r&7)
//  stage : 32768 = double-buffered staging (conS / Gs), 16K per buffer.
//          Epilogue reductions (w12s 8K, nsqS 1K, red) overlay this region.
//  total : 163840 = 160 KiB.
// Shape is boxed (R15/R16 evidence): 512 threads / 8 waves / 2 per SIMD is
// the ONLY config where acc (128 AGPR) + working set fit the 256-reg/wave
// budget. 16-wave blocks cap at 128 regs/wave -> spill (R16: WRITE_SIZE
// 10KB -> 24.5MB); M=64 wave tiles need 128 AGPR + 32 af VGPR -> spill (R15).
#define STAGE_OFF 131072
#define SMEM_TOTAL 163840

typedef short v8s __attribute__((ext_vector_type(8)));
typedef float v4f __attribute__((ext_vector_type(4)));
typedef const __attribute__((address_space(1))) void* gas1_t;
typedef __attribute__((address_space(3))) void* las3_t;

__device__ __forceinline__ void gl2lds16(const void* g, void* l) {
  __builtin_amdgcn_global_load_lds((gas1_t)g, (las3_t)l, 16, 0, 0);
}

__device__ __forceinline__ unsigned short f2bf(float x) {
  unsigned int u = __float_as_uint(x);
  u = (u + 0x7fffu + ((u >> 16) & 1u)) >> 16;  // RNE
  return (unsigned short)u;
}
__device__ __forceinline__ float bf2f(unsigned short h) {
  return __uint_as_float(((unsigned int)h) << 16);
}

// Packed RNE f32x2 -> bf16x2 (v_cvt_pk_bf16_f32 on gfx950); a -> low 16.
__device__ __forceinline__ unsigned int pkbf(float a, float b) {
  __hip_bfloat162 h = __float22bfloat162_rn(make_float2(a, b));
  unsigned int u;
  __builtin_memcpy(&u, &h, sizeof(u));
  return u;
}

// Staging buffers ([256][32] shorts): 16B chunks XOR-swizzled with (r>>1)&3.
// Writes absorb the swizzle in the global fetch column; reads via this helper.
__device__ __forceinline__ const v8s* stgFrag(const unsigned short* buf, int r,
                                              int quad) {
  return (const v8s*)(buf + r * 32 + ((quad ^ ((r >> 1) & 3)) << 3));
}

// sAt addressing: row-major stride 256 shorts, 16B chunks XOR-swizzled by row.
__device__ __forceinline__ int satIdx(int r, int col) {
  return (r << 8) | ((((col >> 3) ^ (r & 7)) << 3) | (col & 7));
}

// Read an 8-float fragment from the fp32 gram slice [256][64] (32B chunks
// rotated by row) and convert to bf16x8.
__device__ __forceinline__ v8s ldFrag64(const float* buf, int r, int cp) {
  const float* p = buf + r * 64 + (((cp + r) & 7) << 3);
  const float4 x0 = ((const float4*)p)[0];
  const float4 x1 = ((const float4*)p)[1];
  unsigned short h[8];
  h[0] = f2bf(x0.x); h[1] = f2bf(x0.y); h[2] = f2bf(x0.z); h[3] = f2bf(x0.w);
  h[4] = f2bf(x1.x); h[5] = f2bf(x1.y); h[6] = f2bf(x1.z); h[7] = f2bf(x1.w);
  return *(v8s*)h;
}

// ---------------------------------------------------------------------------
// Fused setup: 256 blocks x 512 threads (1 block/CU). Each block: gram
// chunk-0 staging issued first, 1/256th of the bf16 conversions (hides the
// staging latency), then the double-buffered gram K-loop
// (G[n] = laws[n]@laws[n]^T, 32-row output stripe per block).
// ---------------------------------------------------------------------------
__global__ __launch_bounds__(512) void setup_kernel(
    const float* __restrict__ con, const float* __restrict__ laws,
    unsigned short* __restrict__ lawsB, unsigned short* __restrict__ conB,
    float* __restrict__ cnorm, unsigned short* __restrict__ G) {
  extern __shared__ float slice[];  // 2 x [256*64] fp32, row-rotated 32B chunks
  const int bid = blockIdx.x;       // 256 blocks
  const int t = threadIdx.x;
  const int n = bid >> 3;
  const int m0 = (bid & 7) << 5;  // 32-row output stripe of G[n]
  const int lane = t & 63;
  const int w = t >> 6;
  const int quad = lane >> 4;
  const int l16 = lane & 15;
  const int rg = w >> 2;  // 0..1
  const int cg = w & 3;   // 0..3
  const float* lawN = laws + n * (LN * DN);

  // (1) Issue gram chunk-0 staging into buf0 (in flight during conversions).
#pragma unroll
  for (int i = 0; i < 8; ++i) {
    const int s = i * 512 + t;
    const int row = s >> 4;
    const int p = s & 15;
    const int srcCol = ((((p >> 1) - row) & 7) << 3) + ((p & 1) << 2);
    gl2lds16(lawN + row * DN + srcCol, (char*)slice + s * 16);
  }

  // (2a) laws fp32 -> bf16: this block's 16384-float slice.
#pragma unroll
  for (int p = 0; p < 4; ++p) {
    const int off = bid * 16384 + p * 4096 + t * 8;
    const float4* src = (const float4*)(laws + off);
    float4 x0 = src[0], x1 = src[1];
    unsigned short h[8];
    h[0] = f2bf(x0.x); h[1] = f2bf(x0.y); h[2] = f2bf(x0.z); h[3] = f2bf(x0.w);
    h[4] = f2bf(x1.x); h[5] = f2bf(x1.y); h[6] = f2bf(x1.z); h[7] = f2bf(x1.w);
    *(v8s*)(lawsB + off) = *(v8s*)h;
  }
  // (2b) contracts fp32 -> bf16 + row norms: 32 rows (one wave-row per pass).
#pragma unroll
  for (int p = 0; p < 4; ++p) {
    const int r = bid * 32 + p * 8 + w;
    const float4* src = (const float4*)(con + r * DN + lane * 8);
    float4 x0 = src[0], x1 = src[1];
    unsigned short h[8];
    h[0] = f2bf(x0.x); h[1] = f2bf(x0.y); h[2] = f2bf(x0.z); h[3] = f2bf(x0.w);
    h[4] = f2bf(x1.x); h[5] = f2bf(x1.y); h[6] = f2bf(x1.z); h[7] = f2bf(x1.w);
    *(v8s*)(conB + r * DN + lane * 8) = *(v8s*)h;
    float s = x0.x * x0.x + x0.y * x0.y + x0.z * x0.z + x0.w * x0.w +
              x1.x * x1.x + x1.y * x1.y + x1.z * x1.z + x1.w * x1.w;
#pragma unroll
    for (int m = 1; m < 64; m <<= 1) s += __shfl_xor(s, m, 64);
    if (lane == 0) cnorm[r] = sqrtf(s);
  }

  // (3) Gram K-loop, double-buffered.
  v4f acc[4];
#pragma unroll
  for (int b = 0; b < 4; ++b) acc[b] = (v4f){0.f, 0.f, 0.f, 0.f};

  for (int ch = 0; ch < 8; ++ch) {
    __syncthreads();  // buf[ch&1] staged (chunk-ch load has been in flight)
    if (ch < 7) {     // prefetch chunk ch+1 into the other buffer
      const int dk = (ch + 1) << 6;
      char* dst = (char*)slice + ((ch + 1) & 1) * 65536;
#pragma unroll
      for (int i = 0; i < 8; ++i) {
        const int s = i * 512 + t;
        const int row = s >> 4;
        const int p = s & 15;
        const int srcCol = ((((p >> 1) - row) & 7) << 3) + ((p & 1) << 2);
        gl2lds16(lawN + row * DN + dk + srcCol, dst + s * 16);
      }
    }
    const float* buf = slice + (ch & 1) * 16384;
#pragma unroll
    for (int step = 0; step < 2; ++step) {
      const int cp = quad + (step << 2);
      v8s af = ldFrag64(buf, m0 + rg * 16 + l16, cp);
#pragma unroll
      for (int ct = 0; ct < 4; ++ct) {
        v8s bf = ldFrag64(buf, cg * 64 + ct * 16 + l16, cp);
        acc[ct] = __builtin_amdgcn_mfma_f32_16x16x32_bf16(af, bf, acc[ct], 0, 0, 0);
      }
    }
  }
  unsigned short* g = G + n * (LN * LN);
#pragma unroll
  for (int ct = 0; ct < 4; ++ct)
#pragma unroll
    for (int reg = 0; reg < 4; ++reg) {
      const int l = m0 + rg * 16 + quad * 4 + reg;
      g[l * LN + cg * 64 + ct * 16 + l16] = f2bf(acc[ct][reg]);
    }
}

// ---------------------------------------------------------------------------
// Main: one block per (n,c), 512 threads (8 waves). R17 structure (best
// measured: 148.7us) + R18: (1) s_setprio(1) around the MFMA bursts in both
// phases (T5 -- 2 waves/SIMD drift into different roles between barriers;
// priority keeps the matrix pipe fed); (2) G chunks 0 AND 1 hoisted before
// the softmax (both buffers fill under softmax VALU; phase-B loop prefetches
// ch+1 only for ch >= 1 into the buffer freed by the top-of-ch barrier).
// ---------------------------------------------------------------------------
__global__ __launch_bounds__(512, 2) void main_kernel(
    const int* __restrict__ law_lens, const unsigned short* __restrict__ lawsB,
    const unsigned short* __restrict__ conB, const unsigned short* __restrict__ Gm,
    const float* __restrict__ cnorm, float* __restrict__ out) {
  extern __shared__ char smem[];
  unsigned short* sAt = (unsigned short*)smem;  // [256][256] swizzled
  char* stage = smem + STAGE_OFF;               // 2 x 16K buffers

  const int bid = blockIdx.x;
  const int n = bid >> 5;  // 32 consecutive blocks share one n
  const int c = bid & 31;
  const int t = threadIdx.x;
  const int lane = t & 63;
  const int w = t >> 6;  // wave 0..7
  const int quad = lane >> 4;
  const int l16 = lane & 15;
  const int sub = t & 3;
  const int rQ = t >> 2;                   // 0..127
  const int subx = sub ^ ((rQ >> 1) & 3);  // swizzled source chunk
  const int len = law_lens[n];
  const int nCh = (len + 31) >> 5;         // phase-B k-chunks (block-uniform)
  const bool active = (w * 32) < len;      // wave has live l-rows in phase A

  const unsigned short* lawN = lawsB + n * (LN * DN);
  const unsigned short* conC = conB + c * (RN * DN);
  const unsigned short* Gn = Gm + n * (LN * LN);

  float w12p[16];
#pragma unroll
  for (int i = 0; i < 16; ++i) w12p[i] = 0.f;

  // ---------------- Phase A ----------------
  {
    const unsigned short* a0p = lawN + (w * 32 + l16) * DN + quad * 8;
    const unsigned short* a1p = a0p + 16 * DN;

    v4f acc[2][16];
#pragma unroll
    for (int a = 0; a < 2; ++a)
#pragma unroll
      for (int b = 0; b < 16; ++b) acc[a][b] = (v4f){0.f, 0.f, 0.f, 0.f};

    // Prologue: stage con chunk 0 into buf0 + load af(chunk 0) into afA.
#pragma unroll
    for (int i = 0; i < 2; ++i)
      gl2lds16(conC + (i * 128 + rQ) * DN + subx * 8,
               stage + i * 8192 + t * 16);
    v8s afA0 = *(const v8s*)(a0p);
    v8s afA1 = *(const v8s*)(a1p);

#pragma unroll
    for (int ch = 0; ch < 16; ch += 2) {
      // ---- even chunk ch: compute from buf0 with afA; prefetch ch+1 ----
      __syncthreads();  // drains chunk-ch staging + afA loads (all overlapped)
      v8s afB0, afB1;
      {
        const int dkn = (ch + 1) << 5;  // ch+1 <= 15 always here
#pragma unroll
        for (int i = 0; i < 2; ++i)
          gl2lds16(conC + (i * 128 + rQ) * DN + dkn + subx * 8,
                   stage + 16384 + i * 8192 + t * 16);
        afB0 = *(const v8s*)(a0p + dkn);
        afB1 = *(const v8s*)(a1p + dkn);
      }
      __builtin_amdgcn_sched_barrier(0);
      if (active) {  // wave-uniform: inactive waves produce only zeros below
        const unsigned short* cs = (const unsigned short*)stage;
        __builtin_amdgcn_s_setprio(1);
#pragma unroll
        for (int rt = 0; rt < 16; ++rt) {
          v8s bf = *stgFrag(cs, rt * 16 + l16, quad);
          acc[0][rt] = __builtin_amdgcn_mfma_f32_16x16x32_bf16(afA0, bf, acc[0][rt], 0, 0, 0);
          acc[1][rt] = __builtin_amdgcn_mfma_f32_16x16x32_bf16(afA1, bf, acc[1][rt], 0, 0, 0);
        }
        __builtin_amdgcn_s_setprio(0);
      }
      // ---- odd chunk ch+1: compute from buf1 with afB; prefetch ch+2 ----
      __syncthreads();  // drains chunk-(ch+1) staging + afB loads
      if (ch + 2 < 16) {
        const int dkn = (ch + 2) << 5;
#pragma unroll
        for (int i = 0; i < 2; ++i)
          gl2lds16(conC + (i * 128 + rQ) * DN + dkn + subx * 8,
                   stage + i * 8192 + t * 16);
        afA0 = *(const v8s*)(a0p + dkn);
        afA1 = *(const v8s*)(a1p + dkn);
      }
      __builtin_amdgcn_sched_barrier(0);
      if (active) {
        const unsigned short* cs = (const unsigned short*)(stage + 16384);
        __builtin_amdgcn_s_setprio(1);
#pragma unroll
        for (int rt = 0; rt < 16; ++rt) {
          v8s bf = *stgFrag(cs, rt * 16 + l16, quad);
          acc[0][rt] = __builtin_amdgcn_mfma_f32_16x16x32_bf16(afB0, bf, acc[0][rt], 0, 0, 0);
          acc[1][rt] = __builtin_amdgcn_mfma_f32_16x16x32_bf16(afB1, bf, acc[1][rt], 0, 0, 0);
        }
        __builtin_amdgcn_s_setprio(0);
      }
    }

    __syncthreads();  // all staging reads done; both stage buffers reusable

    // Hoisted: stage G chunks 0 AND 1 NOW (buf0 and buf1) -- latency hides
    // under the softmax VALU below; phase B's first barrier drains both.
#pragma unroll
    for (int i = 0; i < 2; ++i)
      gl2lds16(Gn + (i * 128 + rQ) * LN + subx * 8, stage + i * 8192 + t * 16);
#pragma unroll
    for (int i = 0; i < 2; ++i)
      gl2lds16(Gn + (i * 128 + rQ) * LN + 32 + subx * 8,
               stage + 16384 + i * 8192 + t * 16);

    if (active) {
      // Softmax row ops (streaming; |lv*inv| <= 1 so exp needs no max-sub).
      // Row l lives in 16 lanes (C layout col=lane&15 -> r index). 4 regs =
      // 4 consecutive sAt columns -> packed cvt + b64 writes.
#pragma unroll
      for (int tl = 0; tl < 2; ++tl) {
        unsigned int pk[16][2];
        float a0s[16];
#pragma unroll
        for (int reg = 0; reg < 4; ++reg) {
          const int lg = w * 32 + tl * 16 + quad * 4 + reg;
          float ss = 0.f;
#pragma unroll
          for (int rt = 0; rt < 16; ++rt) {
            const float v = acc[tl][rt][reg] * 0.04419417382415922f;
            const float lv = v > 0.f ? v : 0.1f * v;
            ss += lv * lv;
          }
#pragma unroll
          for (int m = 1; m < 16; m <<= 1) ss += __shfl_xor(ss, m, 64);
          const float inv = 1.f / (sqrtf(ss) + 1e-8f);
          float e[16];
          float den = 0.f;
#pragma unroll
          for (int rt = 0; rt < 16; ++rt) {
            const float v = acc[tl][rt][reg] * 0.04419417382415922f;
            const float lv = v > 0.f ? v : 0.1f * v;
            e[rt] = __expf(lv * inv);
            den += e[rt];
          }
#pragma unroll
          for (int m = 1; m < 16; m <<= 1) den += __shfl_xor(den, m, 64);
          const float sc = (lg < len) ? 4.f / den : 0.f;  // SMOOTH, masked
#pragma unroll
          for (int rt = 0; rt < 16; ++rt) {
            const float v = acc[tl][rt][reg] * 0.04419417382415922f;
            const float a = e[rt] * sc;
            w12p[rt] += a * v;  // raw S -> cosine numerator
            if (reg & 1)
              pk[rt][reg >> 1] = pkbf(a0s[rt], a);
            else
              a0s[rt] = a;
          }
        }
        const int lg0 = w * 32 + tl * 16 + quad * 4;
#pragma unroll
        for (int rt = 0; rt < 16; ++rt)
          *(uint2*)(sAt + satIdx(rt * 16 + l16, lg0)) = *(uint2*)pk[rt];
      }
    } else {
      // Zero this wave's sAt columns so nsq's full-width reads see exact
      // zeros (attn == 0 beyond len).
      uint2 z;
      z.x = 0u;
      z.y = 0u;
#pragma unroll
      for (int tl = 0; tl < 2; ++tl) {
        const int lg0 = w * 32 + tl * 16 + quad * 4;
#pragma unroll
        for (int rt = 0; rt < 16; ++rt)
          *(uint2*)(sAt + satIdx(rt * 16 + l16, lg0)) = z;
      }
    }
  }

  // Reduce w12 partials across quads; keep in registers through phase B.
  // (Inactive waves contribute zeros.)
#pragma unroll
  for (int rt = 0; rt < 16; ++rt) {
    w12p[rt] += __shfl_xor(w12p[rt], 16, 64);
    w12p[rt] += __shfl_xor(w12p[rt], 32, 64);
  }

  // ---------------- Phase B (k capped at nCh = ceil(len/32)) ----------------
  float nsv[2][4];
  {
    v4f acc[2][16];
#pragma unroll
    for (int a = 0; a < 2; ++a)
#pragma unroll
      for (int b = 0; b < 16; ++b) acc[a][b] = (v4f){0.f, 0.f, 0.f, 0.f};

    __syncthreads();  // sAt writes complete; G chunks 0,1 staged (drained)

    for (int ch = 0; ch < nCh; ++ch) {
      const int lk = ch << 5;
      if (ch) __syncthreads();  // drains chunk-ch staging; frees buf[(ch+1)&1]
      v8s af0 = *(const v8s*)(sAt + satIdx(w * 32 + l16, lk + quad * 8));
      v8s af1 = *(const v8s*)(sAt + satIdx(w * 32 + 16 + l16, lk + quad * 8));
      __builtin_amdgcn_sched_barrier(0);
      if (ch > 0 && ch < nCh - 1) {  // prefetch chunk ch+1 (ch0/ch1 hoisted)
        char* dst = stage + ((ch + 1) & 1) * 16384;
#pragma unroll
        for (int i = 0; i < 2; ++i)
          gl2lds16(Gn + (i * 128 + rQ) * LN + (lk + 32) + subx * 8,
                   dst + i * 8192 + t * 16);
      }
      __builtin_amdgcn_sched_barrier(0);
      const unsigned short* gs =
          (const unsigned short*)(stage + (ch & 1) * 16384);
      __builtin_amdgcn_s_setprio(1);
#pragma unroll
      for (int lt = 0; lt < 16; ++lt) {
        v8s bf = *stgFrag(gs, lt * 16 + l16, quad);  // G row (symmetric)
        acc[0][lt] = __builtin_amdgcn_mfma_f32_16x16x32_bf16(af0, bf, acc[0][lt], 0, 0, 0);
        acc[1][lt] = __builtin_amdgcn_mfma_f32_16x16x32_bf16(af1, bf, acc[1][lt], 0, 0, 0);
      }
      __builtin_amdgcn_s_setprio(0);
    }
    // nsq[r] = sum_l At[r,l] * U[r,l] (sAt cols >= len are exact zeros)
#pragma unroll
    for (int tl = 0; tl < 2; ++tl) {
#pragma unroll
      for (int reg = 0; reg < 4; ++reg) {
        const int r = w * 32 + tl * 16 + quad * 4 + reg;
        float s = 0.f;
#pragma unroll
        for (int lt = 0; lt < 16; ++lt)
          s += acc[tl][lt][reg] * bf2f(sAt[satIdx(r, lt * 16 + l16)]);
#pragma unroll
        for (int m = 1; m < 16; m <<= 1) s += __shfl_xor(s, m, 64);
        nsv[tl][reg] = s;
      }
    }
  }

  // ---------------- Phase C (reductions overlay the stage region) ----------
  float* w12s = (float*)stage;           // [8][256] = 8K
  float* nsqS = (float*)(stage + 8192);  // [256]    = 1K
  float* red = (float*)(stage + 9216);   // [8]
  __syncthreads();  // all Gs reads done; stage is free for reductions
  if (l16 == 0) {
#pragma unroll
    for (int tl = 0; tl < 2; ++tl)
#pragma unroll
      for (int reg = 0; reg < 4; ++reg)
        nsqS[w * 32 + tl * 16 + quad * 4 + reg] = nsv[tl][reg];
  }
  if (lane < 16) {
#pragma unroll
    for (int rt = 0; rt < 16; ++rt) w12s[w * 256 + rt * 16 + lane] = w12p[rt];
  }
  __syncthreads();
  float p = 0.f;
  if (t < 256) {
    float w12 = 0.f;
#pragma unroll
    for (int i = 0; i < 8; ++i) w12 += w12s[i * 256 + t];
    const float w1 = cnorm[c * RN + t];
    const float w2 = sqrtf(fmaxf(nsqS[t], 0.f));
    const float sim = (w12 * 22.627416997969522f) / fmaxf(w1 * w2, 1e-8f);
    p = __expf(6.f * sim);
  }
#pragma unroll
  for (int m = 1; m < 64; m <<= 1) p += __shfl_xor(p, m, 64);
  if (lane == 0) red[w] = p;
  __syncthreads();
  if (t == 0) {
    float s = 0.f;
#pragma unroll
    for (int i = 0; i < 8; ++i) s += red[i];
    out[c * NN + n] = logf(s) / 6.f;
  }
}

// ---------------------------------------------------------------------------
extern "C" void kernel_launch(void* const* d_in, const int* in_sizes, int n_in,
                              void* d_out, int out_size, void* d_ws, size_t ws_size,
                              hipStream_t stream) {
  (void)in_sizes; (void)n_in; (void)out_size;
  const float* contracts = (const float*)d_in[0];
  const float* laws = (const float*)d_in[1];
  const int* law_lens = (const int*)d_in[2];
  float* out = (float*)d_out;

  // Workspace layout (21,004,288 B total)
  unsigned short* lawsB = (unsigned short*)d_ws;  // 8 MiB
  unsigned short* conB = lawsB + NN * LN * DN;    // 8 MiB
  unsigned short* G = conB + CN * RN * DN;        // 4 MiB
  float* cnorm = (float*)(G + NN * LN * LN);      // 32 KiB
  if (ws_size < (size_t)21004288) return;

  hipFuncSetAttribute((const void*)setup_kernel,
                      hipFuncAttributeMaxDynamicSharedMemorySize, 131072);
  hipFuncSetAttribute((const void*)main_kernel,
                      hipFuncAttributeMaxDynamicSharedMemorySize, SMEM_TOTAL);

  // 256 blocks: gram stripe + 1/256th of the bf16 conversions each.
  setup_kernel<<<256, 512, 131072, stream>>>(contracts, laws, lawsB, conB,
                                             cnorm, G);
  main_kernel<<<1024, 512, SMEM_TOTAL, stream>>>(law_lens, lawsB, conB, G,
                                                 cnorm, out);
}